// Round 11
// baseline (61.883 us; speedup 1.0000x reference)
//
#include <hip/hip_runtime.h>
#include <hip/hip_bf16.h>

#define A_ 8
#define B_ 256
#define I_ 256
#define J_ 256
#define K_ 256

typedef __attribute__((ext_vector_type(8))) short short8_t;
typedef __attribute__((ext_vector_type(4))) float f32x4_t;
typedef __attribute__((ext_vector_type(4))) uint u32x4_t;

static __device__ __forceinline__ uint pack2bf(float a, float b) {
  float2 f2; f2.x = a; f2.y = b;
  __hip_bfloat162 h2 = __float22bfloat162_rn(f2);
  uint r;
  __builtin_memcpy(&r, &h2, 4);
  return r;
}

static __device__ __forceinline__ ushort f2bf(float f) {
  __hip_bfloat16 h = __float2bfloat16(f);
  ushort us;
  __builtin_memcpy(&us, &h, 2);
  return us;
}

static __device__ __forceinline__ float bf2f(ushort h) {
  uint u = ((uint)h) << 16;
  float f;
  __builtin_memcpy(&f, &u, 4);
  return f;
}

// ---------------------------------------------------------------------------
// Prepass C: cbf[b][j] = bf16(c[b][j])
// ---------------------------------------------------------------------------
__global__ __launch_bounds__(256) void prepass_c_kernel(
    const float* __restrict__ c, ushort* __restrict__ cbf) {
  const int idx = blockIdx.x * 256 + threadIdx.x;
  const f32x4_t v = *reinterpret_cast<const f32x4_t*>(c + (size_t)idx * 4);
  uint2 r;
  r.x = pack2bf(v[0], v[1]);
  r.y = pack2bf(v[2], v[3]);
  *reinterpret_cast<uint2*>(cbf + (size_t)idx * 4) = r;
}

// ---------------------------------------------------------------------------
// Prepass W2: wt2[i][js][k][jj] = bf16(w[i][js*8+jj][k])   (js=j>>3, jj=j&7)
// i.e. w pre-packed in EXACT MFMA B-fragment order, so the GEMM's B-frag
// wave-load is 4 x 256B fully-dense segments (the fix for 10 rounds of
// sub-128B-segment read amplification).
// Reads contiguous (R6-proven pattern), writes contiguous (thread=k).
// Grid (i=256, jc=8) = 2048 blocks, 6/CU.
// ---------------------------------------------------------------------------
__global__ __launch_bounds__(256, 6) void prepass_w2_kernel(
    const float* __restrict__ w, ushort* __restrict__ wt2) {
  const int i   = blockIdx.x;
  const int jc  = blockIdx.y;
  const int tid = threadIdx.x;
  const int jp  = tid & 15;   // j-pair within chunk (0..15)
  const int ks  = tid >> 4;   // k-segment of 16 (0..15)
  __shared__ uint T[256][17];  // [k][jpair] pair-packed bf16, padded

  const float* wi = w + (size_t)i * (J_ * K_);

  // read: rows j = jc*32 + jp*2 (+1), 64B contiguous per thread per row
  const int j = jc * 32 + jp * 2;
  f32x4_t r0[4], r1[4];
#pragma unroll
  for (int q = 0; q < 4; q++) {
    r0[q] = *reinterpret_cast<const f32x4_t*>(wi + (size_t)j * K_ + ks * 16 + q * 4);
    r1[q] = *reinterpret_cast<const f32x4_t*>(wi + (size_t)(j + 1) * K_ + ks * 16 + q * 4);
  }
#pragma unroll
  for (int q = 0; q < 4; q++)
#pragma unroll
    for (int e = 0; e < 4; e++)
      T[ks * 16 + q * 4 + e][jp] = pack2bf(r0[q][e], r1[q][e]);
  __syncthreads();

  // write: thread = k; 4 j-slices of 8 -> one uint4 (16B) each, contiguous
  const int k = tid;
#pragma unroll
  for (int js = 0; js < 4; js++) {
    u32x4_t vv;
#pragma unroll
    for (int p = 0; p < 4; p++) vv[p] = T[k][js * 4 + p];
    *reinterpret_cast<u32x4_t*>(
        wt2 + (((size_t)i * 32 + jc * 4 + js) * K_ + k) * 8) = vv;
  }
}

// ---------------------------------------------------------------------------
// Pass 1: u[b][i][k] = sum_j c[b][j] * w[i][j][k]   (u stored bf16 [b][i][k])
// ZERO LDS, ZERO barriers. Grid (i, k-quarter) = (256,4); 256 thr = 4 waves,
// wave = 64(b) x 64(k), acc[4][4]. 4 blocks/CU; waves fully independent.
// A-frags: b128 direct from L2-hot cbf (pattern proven rounds 3/7/10).
// B-frags: b128 direct from wt2 -- 16 lanes x 16B = 256B dense segments.
// 8 straight-line j-steps, compiler-scheduled (no sync anywhere).
// ---------------------------------------------------------------------------
__global__ __launch_bounds__(256, 4) void pass1_kernel(
    const ushort* __restrict__ cbf, const ushort* __restrict__ wt2,
    ushort* __restrict__ u) {
  const int i    = blockIdx.x;
  const int kq   = blockIdx.y;      // k quarter (0..3)
  const int tid  = threadIdx.x;
  const int lane = tid & 63;
  const int wv   = tid >> 6;        // b-quadrant (0..3)
  const int lrow = lane & 15;
  const int lhi  = lane >> 4;       // 0..3

  const int arow = wv * 64 + lrow;
  const ushort* wbase =
      wt2 + (size_t)i * (J_ * K_) + ((size_t)(kq * 64 + lrow)) * 8 +
      (size_t)lhi * (K_ * 8);  // + t*4*(K_*8) + n*16*8 per access

  f32x4_t acc[4][4];
#pragma unroll
  for (int m = 0; m < 4; m++)
#pragma unroll
    for (int n = 0; n < 4; n++) acc[m][n] = (f32x4_t)(0.0f);

#pragma unroll
  for (int t = 0; t < 8; ++t) {
    short8_t af[4], bf[4];
#pragma unroll
    for (int m = 0; m < 4; m++)
      af[m] = *reinterpret_cast<const short8_t*>(
          cbf + (size_t)(arow + m * 16) * J_ + t * 32 + lhi * 8);
#pragma unroll
    for (int n = 0; n < 4; n++)
      bf[n] = *reinterpret_cast<const short8_t*>(
          wbase + ((size_t)t * 4) * (K_ * 8) + (size_t)(n * 16) * 8);
#pragma unroll
    for (int m = 0; m < 4; m++)
#pragma unroll
      for (int n = 0; n < 4; n++)
        acc[m][n] = __builtin_amdgcn_mfma_f32_16x16x32_bf16(af[m], bf[n],
                                                            acc[m][n], 0, 0, 0);
  }

  // epilogue: u[b][i][k] bf16 (mapping identical to rounds 3/7/10)
#pragma unroll
  for (int m = 0; m < 4; m++) {
    const int brow = wv * 64 + m * 16 + lhi * 4;
#pragma unroll
    for (int n = 0; n < 4; n++) {
      const int kc = kq * 64 + n * 16 + lrow;
      ushort* up = u + ((size_t)brow * I_ + i) * K_ + kc;
#pragma unroll
      for (int r = 0; r < 4; r++)
        up[(size_t)r * (I_ * K_)] = f2bf(acc[m][n][r]);
    }
  }
}

// ---------------------------------------------------------------------------
// Pass 2: out[a][b][k] = sum_i s[a][b][i] * u[b][i][k] + bias[k]
// (round-3 proven version) Grid (B, 2): block handles 4 a's.
// ---------------------------------------------------------------------------
__global__ __launch_bounds__(256) void pass2_kernel(
    const float* __restrict__ s, const ushort* __restrict__ u,
    const float* __restrict__ bias, float* __restrict__ out) {
  const int b   = blockIdx.x;
  const int a0  = blockIdx.y * 4;
  const int tid = threadIdx.x;
  __shared__ float s_l[4][I_];
  __shared__ float red[8][4][K_];

#pragma unroll
  for (int v = 0; v < 4; v++) {
    const int idx = tid + v * 256;
    const int a = idx >> 8, ii = idx & 255;
    s_l[a][ii] = s[((size_t)(a0 + a) * B_ + b) * I_ + ii];
  }
  __syncthreads();

  const int kb = (tid & 31) * 8;
  const int ig = tid >> 5;
  float acc[4][8];
#pragma unroll
  for (int a = 0; a < 4; a++)
#pragma unroll
    for (int q = 0; q < 8; q++) acc[a][q] = 0.0f;

  const ushort* ub = u + ((size_t)b * I_ + ig * 32) * K_ + kb;
  for (int ii = 0; ii < 32; ++ii) {
    const short8_t uv = *reinterpret_cast<const short8_t*>(ub + (size_t)ii * K_);
    float f[8];
#pragma unroll
    for (int q = 0; q < 8; q++) f[q] = bf2f((ushort)uv[q]);
    const int i = ig * 32 + ii;
#pragma unroll
    for (int a = 0; a < 4; a++) {
      const float sa = s_l[a][i];
#pragma unroll
      for (int q = 0; q < 8; q++) acc[a][q] += sa * f[q];
    }
  }

#pragma unroll
  for (int a = 0; a < 4; a++) {
    f32x4_t r0, r1;
#pragma unroll
    for (int q = 0; q < 4; q++) { r0[q] = acc[a][q]; r1[q] = acc[a][4 + q]; }
    *reinterpret_cast<f32x4_t*>(&red[ig][a][kb])     = r0;
    *reinterpret_cast<f32x4_t*>(&red[ig][a][kb + 4]) = r1;
  }
  __syncthreads();

#pragma unroll
  for (int v = 0; v < 4; v++) {
    const int k = tid;
    float sum = 0.0f;
#pragma unroll
    for (int g = 0; g < 8; g++) sum += red[g][v][k];
    out[((size_t)(a0 + v) * B_ + b) * K_ + k] = sum + bias[k];
  }
}

// ---------------------------------------------------------------------------
// Fallback (slow but correct, fp32): used only if workspace is too small.
// ---------------------------------------------------------------------------
__global__ __launch_bounds__(256) void fallback_kernel(
    const float* __restrict__ s, const float* __restrict__ cmat,
    const float* __restrict__ w, const float* __restrict__ bias,
    float* __restrict__ out) {
  const int b = blockIdx.x;
  const int k = threadIdx.x;
  __shared__ float c_l[J_];
  __shared__ float s_l[A_][I_];
  for (int idx = threadIdx.x; idx < J_; idx += 256) c_l[idx] = cmat[(size_t)b * J_ + idx];
  for (int idx = threadIdx.x; idx < A_ * I_; idx += 256) {
    const int a = idx >> 8;
    const int i = idx & 255;
    s_l[a][i] = s[(size_t)a * (B_ * I_) + (size_t)b * I_ + i];
  }
  __syncthreads();
  float acc[A_];
#pragma unroll
  for (int a = 0; a < A_; a++) acc[a] = 0.0f;
  for (int i = 0; i < I_; i++) {
    const float* wrow = w + (size_t)i * (J_ * K_) + k;
    float inner = 0.0f;
    for (int j = 0; j < J_; j++) inner += c_l[j] * wrow[(size_t)j * K_];
#pragma unroll
    for (int a = 0; a < A_; a++) acc[a] += s_l[a][i] * inner;
  }
#pragma unroll
  for (int a = 0; a < A_; a++)
    out[((size_t)a * B_ + b) * K_ + k] = acc[a] + bias[k];
}

extern "C" void kernel_launch(void* const* d_in, const int* in_sizes, int n_in,
                              void* d_out, int out_size, void* d_ws, size_t ws_size,
                              hipStream_t stream) {
  const float* s    = (const float*)d_in[0];  // (A,B,I)
  const float* cmat = (const float*)d_in[1];  // (B,J)
  const float* w    = (const float*)d_in[2];  // (I,J,K)
  const float* bias = (const float*)d_in[3];  // (K,)
  float* out = (float*)d_out;

  const size_t u_elems   = (size_t)B_ * I_ * K_;  // 16.7M halves
  const size_t wt_elems  = (size_t)I_ * J_ * K_;  // 16.7M halves
  const size_t cbf_elems = (size_t)B_ * J_;
  const size_t need = (u_elems + wt_elems + cbf_elems) * sizeof(ushort);  // ~67 MB

  if (ws_size >= need) {
    ushort* u   = (ushort*)d_ws;
    ushort* wt2 = (ushort*)d_ws + u_elems;
    ushort* cbf = (ushort*)d_ws + u_elems + wt_elems;
    prepass_c_kernel<<<dim3((B_ * J_) / (256 * 4)), dim3(256), 0, stream>>>(cmat, cbf);
    prepass_w2_kernel<<<dim3(I_, 8), dim3(256), 0, stream>>>(w, wt2);
    pass1_kernel<<<dim3(I_, 4), dim3(256), 0, stream>>>(cbf, wt2, u);
    pass2_kernel<<<dim3(B_, 2), dim3(256), 0, stream>>>(s, u, bias, out);
  } else {
    fallback_kernel<<<dim3(B_), dim3(256), 0, stream>>>(s, cmat, w, bias, out);
  }
}